// Round 2
// baseline (332.488 us; speedup 1.0000x reference)
//
#include <hip/hip_runtime.h>

#define D_IN 512
#define D_OUT 256
#define BM 128
#define BN 128
#define BK 32

typedef short short8 __attribute__((ext_vector_type(8)));
typedef float floatx4 __attribute__((ext_vector_type(4)));

static __device__ __forceinline__ unsigned short f2bf(float f) {
    unsigned u = __float_as_uint(f);
    u += 0x7FFF + ((u >> 16) & 1);
    return (unsigned short)(u >> 16);
}
static __device__ __forceinline__ float bf2f(unsigned short h) {
    return __uint_as_float((unsigned)h << 16);
}

// ---------------- fused: W convert+transpose + cnt zeroing ----------------
// blocks [0, 256): Wt[n][k] = bf16(W[k][n]);  blocks [256, ...): cnt[i] = 0
#define CONV_BLOCKS 256
__global__ __launch_bounds__(512) void convert_and_zero(const float* __restrict__ W,
                                                        unsigned short* __restrict__ Wt,
                                                        int* __restrict__ cnt, int M) {
    int b = blockIdx.x;
    if (b < CONV_BLOCKS) {
        int t = b * 512 + threadIdx.x;     // D_IN*D_OUT = 131072 = 256*512
        int n = t >> 9;
        int k = t & 511;
        Wt[t] = f2bf(W[(size_t)k * D_OUT + n]);
    } else {
        int i = (b - CONV_BLOCKS) * 512 + threadIdx.x;
        if (i < M) cnt[i] = 0;
    }
}

// ---------------- CSR build: histogram + scan ----------------
__global__ __launch_bounds__(256) void hist_rows(const int* __restrict__ rows,
                                                 int* __restrict__ cnt, int E) {
    int e = blockIdx.x * 256 + threadIdx.x;
    if (e < E) atomicAdd(&cnt[rows[e]], 1);
}

#define SCAN_B 4096
__global__ __launch_bounds__(1024) void scan_blocks(const int* __restrict__ cnt,
                                                    int* __restrict__ ptr,
                                                    int* __restrict__ partials, int M) {
    __shared__ int wsum[16];
    const int t = threadIdx.x, lane = t & 63, wave = t >> 6;
    const int base = blockIdx.x * SCAN_B + t * 4;
    int4 v = make_int4(0, 0, 0, 0);
    if (base + 3 < M) v = *(const int4*)(cnt + base);
    else {
        if (base + 0 < M) v.x = cnt[base + 0];
        if (base + 1 < M) v.y = cnt[base + 1];
        if (base + 2 < M) v.z = cnt[base + 2];
        if (base + 3 < M) v.w = cnt[base + 3];
    }
    int s = v.x + v.y + v.z + v.w;
    int incl = s;
#pragma unroll
    for (int off = 1; off < 64; off <<= 1) {
        int x = __shfl_up(incl, off, 64);
        if (lane >= off) incl += x;
    }
    if (lane == 63) wsum[wave] = incl;
    __syncthreads();
    if (t == 0) {
        int run = 0;
#pragma unroll
        for (int w = 0; w < 16; ++w) { int x = wsum[w]; wsum[w] = run; run += x; }
        partials[blockIdx.x] = run;   // raw block total (prefix folded into add_offsets)
    }
    __syncthreads();
    int e0 = wsum[wave] + (incl - s);
    int e1 = e0 + v.x, e2 = e1 + v.y, e3 = e2 + v.z;
    if (base + 3 < M) *(int4*)(ptr + base) = make_int4(e0, e1, e2, e3);
    else {
        if (base + 0 < M) ptr[base + 0] = e0;
        if (base + 1 < M) ptr[base + 1] = e1;
        if (base + 2 < M) ptr[base + 2] = e2;
        if (base + 3 < M) ptr[base + 3] = e3;
    }
}

// add_offsets with inline prefix over <=13 partials (uniform per block: 256 | 4096)
__global__ __launch_bounds__(256) void add_offsets(int* __restrict__ ptr,
                                                   const int* __restrict__ partials,
                                                   int M) {
    int i = blockIdx.x * 256 + threadIdx.x;
    if (i >= M) return;
    int bucket = blockIdx.x >> 4;       // (i >> 12), constant per block
    int off = 0;
    for (int j = 0; j < bucket; ++j) off += partials[j];
    ptr[i] += off;
}

// ---------------- fused GEMM + edge placement, interleaved 2:1 ----------------
// blockIdx % 3 == 2  -> build role: 2048 edges (4/thread), destructive CSR place
// else               -> gemm role: S(bf16) = bf16(A) @ bf16(W), 128x128 tile
// LDS layout: k-quad planes [q][row][8 elems] -> every 16-lane phase accesses
// 16 contiguous 16B chunks on both write and read side: bank-conflict-free.
__global__ __launch_bounds__(512, 4) void gemm_build(
    const float* __restrict__ A, const unsigned short* __restrict__ Wt,
    unsigned short* __restrict__ S, int M, int nGemm, int nBuild,
    const float* __restrict__ vals, const int* __restrict__ rows,
    const int* __restrict__ cols, int* __restrict__ ptr,
    unsigned long long* __restrict__ edges, int E) {
    __shared__ unsigned short As[4 * BM * 8];   // 8 KB
    __shared__ unsigned short Bs[4 * BN * 8];   // 8 KB
    const int bid = blockIdx.x;
    const int tid = threadIdx.x;
    const int r3  = bid % 3;
    const int p3  = bid / 3;

    if (r3 == 2) {
        // ---- build role ----
        if (p3 >= nBuild) return;
        int e0 = p3 * 2048 + tid;
        int rr[4]; unsigned cc[4], vv[4]; bool ok[4];
#pragma unroll
        for (int i = 0; i < 4; ++i) {
            int e = e0 + i * 512;
            ok[i] = e < E;
            int es = ok[i] ? e : 0;
            rr[i] = rows[es];
            cc[i] = (unsigned)cols[es];
            vv[i] = (unsigned)__float_as_int(vals[es]);
        }
#pragma unroll
        for (int i = 0; i < 4; ++i) {
            if (ok[i]) {
                int pos = atomicAdd(&ptr[rr[i]], 1);
                unsigned long long packed =
                    (unsigned long long)cc[i] | ((unsigned long long)vv[i] << 32);
                __builtin_nontemporal_store(packed, edges + pos);  // no RFO on scatter
            }
        }
        return;
    }

    // ---- gemm role ----
    const int gi = p3 * 2 + r3;
    if (gi >= nGemm) return;
    const int lane = tid & 63;
    const int wave = tid >> 6;
    const int l15  = lane & 15;
    const int quad = lane >> 4;
    const int bm   = (gi >> 1) * BM;
    const int bn   = (gi & 1) * BN;
    const int wm   = (wave >> 2) * 64;
    const int wn   = (wave & 3) * 32;

    // staging coords: thread covers (row sm, k-plane quad) -> 8 elems = 16 B
    const int sm = wave * 16 + l15;              // 0..127
    const bool aval = (bm + sm) < M;
    const float* aptr = A + (size_t)(aval ? bm + sm : 0) * D_IN + quad * 8;
    const unsigned short* bptr = Wt + (size_t)(bn + sm) * D_IN + quad * 8;
    const int soff = (quad * BM + sm) * 8;       // elem offset (16B-aligned), same for A/B

    // prologue: K-tile 0 into registers
    float4 aR0 = aval ? *(const float4*)(aptr + 0) : make_float4(0.f, 0.f, 0.f, 0.f);
    float4 aR1 = aval ? *(const float4*)(aptr + 4) : make_float4(0.f, 0.f, 0.f, 0.f);
    short8 bR  = *(const short8*)bptr;

    floatx4 acc[4][2] = {};

    for (int k0 = 0; k0 < D_IN; k0 += BK) {
        // drain staged regs -> LDS (A converted to bf16)
        short8 a8;
        a8[0] = (short)f2bf(aR0.x); a8[1] = (short)f2bf(aR0.y);
        a8[2] = (short)f2bf(aR0.z); a8[3] = (short)f2bf(aR0.w);
        a8[4] = (short)f2bf(aR1.x); a8[5] = (short)f2bf(aR1.y);
        a8[6] = (short)f2bf(aR1.z); a8[7] = (short)f2bf(aR1.w);
        *(short8*)(As + soff) = a8;
        *(short8*)(Bs + soff) = bR;
        __syncthreads();

        // prefetch next K-tile (hides under frag reads + MFMA + barrier)
        if (k0 + BK < D_IN) {
            aR0 = aval ? *(const float4*)(aptr + k0 + BK + 0) : make_float4(0.f, 0.f, 0.f, 0.f);
            aR1 = aval ? *(const float4*)(aptr + k0 + BK + 4) : make_float4(0.f, 0.f, 0.f, 0.f);
            bR  = *(const short8*)(bptr + k0 + BK);
        }

        short8 af[4], bfr[2];
#pragma unroll
        for (int i = 0; i < 4; ++i)
            af[i] = *(const short8*)(As + (quad * BM + wm + i * 16 + l15) * 8);
#pragma unroll
        for (int j = 0; j < 2; ++j)
            bfr[j] = *(const short8*)(Bs + (quad * BN + wn + j * 16 + l15) * 8);
#pragma unroll
        for (int i = 0; i < 4; ++i)
#pragma unroll
            for (int j = 0; j < 2; ++j)
                acc[i][j] = __builtin_amdgcn_mfma_f32_16x16x32_bf16(
                    af[i], bfr[j], acc[i][j], 0, 0, 0);
        __syncthreads();
    }

    // epilogue: row = bm+wm+i*16+quad*4+r, col = bn+wn+j*16+l15
#pragma unroll
    for (int i = 0; i < 4; ++i) {
#pragma unroll
        for (int r = 0; r < 4; ++r) {
            int gm = bm + wm + i * 16 + quad * 4 + r;
            if (gm < M) {
#pragma unroll
                for (int j = 0; j < 2; ++j)
                    S[(size_t)gm * D_OUT + bn + wn + j * 16 + l15] = f2bf(acc[i][j][r]);
            }
        }
    }
}

// ---------------- Aggregate: one wave/row, 8-edge unroll, fp32 accum ----------------
// Reads shifted (destructive) CSR: row extent = [row ? ptr[row-1] : 0, ptr[row]).
__global__ __launch_bounds__(256) void spmm_rows(const unsigned short* __restrict__ S,
                                                 const int2* __restrict__ edges,
                                                 const int* __restrict__ ptr,
                                                 const float* __restrict__ bias,
                                                 float* __restrict__ out, int M) {
    const int row = blockIdx.x * 4 + (threadIdx.x >> 6);
    if (row >= M) return;
    const int lane = threadIdx.x & 63;
    float4 a0 = ((const float4*)bias)[lane];
    float4 a1 = make_float4(0.f, 0.f, 0.f, 0.f);
    const int beg = row ? ptr[row - 1] : 0;
    const int end = ptr[row];
    int j = beg;
    for (; j + 7 < end; j += 8) {
        int2 e0 = edges[j + 0], e1 = edges[j + 1], e2 = edges[j + 2], e3 = edges[j + 3];
        int2 e4 = edges[j + 4], e5 = edges[j + 5], e6 = edges[j + 6], e7 = edges[j + 7];
        ushort4 s0 = ((const ushort4*)(S + (size_t)e0.x * D_OUT))[lane];
        ushort4 s1 = ((const ushort4*)(S + (size_t)e1.x * D_OUT))[lane];
        ushort4 s2 = ((const ushort4*)(S + (size_t)e2.x * D_OUT))[lane];
        ushort4 s3 = ((const ushort4*)(S + (size_t)e3.x * D_OUT))[lane];
        ushort4 s4 = ((const ushort4*)(S + (size_t)e4.x * D_OUT))[lane];
        ushort4 s5 = ((const ushort4*)(S + (size_t)e5.x * D_OUT))[lane];
        ushort4 s6 = ((const ushort4*)(S + (size_t)e6.x * D_OUT))[lane];
        ushort4 s7 = ((const ushort4*)(S + (size_t)e7.x * D_OUT))[lane];
        float v0 = __int_as_float(e0.y), v1 = __int_as_float(e1.y);
        float v2 = __int_as_float(e2.y), v3 = __int_as_float(e3.y);
        float v4 = __int_as_float(e4.y), v5 = __int_as_float(e5.y);
        float v6 = __int_as_float(e6.y), v7 = __int_as_float(e7.y);
        a0.x += v0 * bf2f(s0.x) + v2 * bf2f(s2.x) + v4 * bf2f(s4.x) + v6 * bf2f(s6.x);
        a0.y += v0 * bf2f(s0.y) + v2 * bf2f(s2.y) + v4 * bf2f(s4.y) + v6 * bf2f(s6.y);
        a0.z += v0 * bf2f(s0.z) + v2 * bf2f(s2.z) + v4 * bf2f(s4.z) + v6 * bf2f(s6.z);
        a0.w += v0 * bf2f(s0.w) + v2 * bf2f(s2.w) + v4 * bf2f(s4.w) + v6 * bf2f(s6.w);
        a1.x += v1 * bf2f(s1.x) + v3 * bf2f(s3.x) + v5 * bf2f(s5.x) + v7 * bf2f(s7.x);
        a1.y += v1 * bf2f(s1.y) + v3 * bf2f(s3.y) + v5 * bf2f(s5.y) + v7 * bf2f(s7.y);
        a1.z += v1 * bf2f(s1.z) + v3 * bf2f(s3.z) + v5 * bf2f(s5.z) + v7 * bf2f(s7.z);
        a1.w += v1 * bf2f(s1.w) + v3 * bf2f(s3.w) + v5 * bf2f(s5.w) + v7 * bf2f(s7.w);
    }
    for (; j + 3 < end; j += 4) {
        int2 e0 = edges[j], e1 = edges[j + 1], e2 = edges[j + 2], e3 = edges[j + 3];
        ushort4 s0 = ((const ushort4*)(S + (size_t)e0.x * D_OUT))[lane];
        ushort4 s1 = ((const ushort4*)(S + (size_t)e1.x * D_OUT))[lane];
        ushort4 s2 = ((const ushort4*)(S + (size_t)e2.x * D_OUT))[lane];
        ushort4 s3 = ((const ushort4*)(S + (size_t)e3.x * D_OUT))[lane];
        float v0 = __int_as_float(e0.y), v1 = __int_as_float(e1.y);
        float v2 = __int_as_float(e2.y), v3 = __int_as_float(e3.y);
        a0.x += v0 * bf2f(s0.x) + v2 * bf2f(s2.x);
        a0.y += v0 * bf2f(s0.y) + v2 * bf2f(s2.y);
        a0.z += v0 * bf2f(s0.z) + v2 * bf2f(s2.z);
        a0.w += v0 * bf2f(s0.w) + v2 * bf2f(s2.w);
        a1.x += v1 * bf2f(s1.x) + v3 * bf2f(s3.x);
        a1.y += v1 * bf2f(s1.y) + v3 * bf2f(s3.y);
        a1.z += v1 * bf2f(s1.z) + v3 * bf2f(s3.z);
        a1.w += v1 * bf2f(s1.w) + v3 * bf2f(s3.w);
    }
    for (; j < end; ++j) {
        int2 e = edges[j];
        float v = __int_as_float(e.y);
        ushort4 s = ((const ushort4*)(S + (size_t)e.x * D_OUT))[lane];
        a0.x += v * bf2f(s.x);
        a0.y += v * bf2f(s.y);
        a0.z += v * bf2f(s.z);
        a0.w += v * bf2f(s.w);
    }
    a0.x += a1.x; a0.y += a1.y; a0.z += a1.z; a0.w += a1.w;
    // out is never re-read: non-temporal store keeps S resident in caches
    floatx4 res = {a0.x, a0.y, a0.z, a0.w};
    __builtin_nontemporal_store(res, (floatx4*)(out + (size_t)row * D_OUT) + lane);
}

extern "C" void kernel_launch(void* const* d_in, const int* in_sizes, int n_in,
                              void* d_out, int out_size, void* d_ws, size_t ws_size,
                              hipStream_t stream) {
    const float* inputs    = (const float*)d_in[0];
    const float* weights   = (const float*)d_in[1];
    const float* bias      = (const float*)d_in[2];
    const float* edge_vals = (const float*)d_in[3];
    const int*   edge_row  = (const int*)d_in[4];
    const int*   edge_col  = (const int*)d_in[5];
    float* out = (float*)d_out;

    const int M = in_sizes[0] / D_IN;  // 50000
    const int E = in_sizes[3];         // 800000

    // Workspace:
    //   S: M*D_OUT bf16 | Wt: D_OUT*D_IN bf16 | edges: E u64 | ptr: M+1 | cnt: M | partials
    char* ws = (char*)d_ws;
    unsigned short* S  = (unsigned short*)ws;
    unsigned short* Wt = (unsigned short*)(ws + (size_t)M * D_OUT * 2);
    unsigned long long* edges = (unsigned long long*)((char*)Wt + (size_t)D_OUT * D_IN * 2);
    int*  ptr          = (int*)((char*)edges + (size_t)E * 8);
    int*  cnt          = ptr + ((M + 4) & ~3);
    int*  partials     = cnt + M;

    // 1) W -> bf16 transposed, fused with cnt zeroing
    int nzero = (M + 511) / 512;
    convert_and_zero<<<CONV_BLOCKS + nzero, 512, 0, stream>>>(weights, Wt, cnt, M);

    // 2) CSR histogram + scan (partial prefix folded into add_offsets)
    hist_rows<<<(E + 255) / 256, 256, 0, stream>>>(edge_row, cnt, E);
    int nb = (M + SCAN_B - 1) / SCAN_B;   // 13
    scan_blocks<<<nb, 1024, 0, stream>>>(cnt, ptr, partials, M);
    add_offsets<<<(M + 255) / 256, 256, 0, stream>>>(ptr, partials, M);

    // 3) GEMM interleaved 2:1 with destructive edge placement
    int nGemm  = 2 * ((M + BM - 1) / BM);   // 782
    int nBuild = (E + 2047) / 2048;         // 391
    int nPair  = nBuild > (nGemm + 1) / 2 ? nBuild : (nGemm + 1) / 2;
    gemm_build<<<3 * nPair, 512, 0, stream>>>(inputs, Wt, S, M, nGemm, nBuild,
                                              edge_vals, edge_row, edge_col,
                                              ptr, edges, E);

    // 4) aggregate (shifted CSR bounds)
    spmm_rows<<<(M + 3) / 4, 256, 0, stream>>>(S, edges != 0 ? (const int2*)edges : (const int2*)edges, ptr, bias, out, M);
}